// Round 1
// baseline (1335.748 us; speedup 1.0000x reference)
//
#include <hip/hip_runtime.h>

typedef __attribute__((ext_vector_type(8))) short short8;
typedef __attribute__((ext_vector_type(4))) float f32x4;
typedef __attribute__((ext_vector_type(4))) unsigned short u16x4;

#define NB 8
#define NQL 2048
#define NKL 2048
#define DD 512

__device__ __forceinline__ unsigned short f2bf(float x){
  unsigned u = __builtin_bit_cast(unsigned, x);
  unsigned r = u + 0x7FFFu + ((u >> 16) & 1u);
  return (unsigned short)(r >> 16);
}
__device__ __forceinline__ float bf2f(unsigned short h){
  unsigned u = ((unsigned)h) << 16;
  return __builtin_bit_cast(float, u);
}

// ---------------- split fp32 -> bf16 hi/lo ----------------
__global__ __launch_bounds__(256) void split_k(const float* __restrict__ x,
    unsigned short* __restrict__ hi, unsigned short* __restrict__ lo, int n4){
  int i = blockIdx.x*256 + threadIdx.x;
  if (i >= n4) return;
  f32x4 v = reinterpret_cast<const f32x4*>(x)[i];
  u16x4 h, l;
  #pragma unroll
  for (int j=0;j<4;j++){
    unsigned short hh = f2bf(v[j]);
    h[j] = hh;
    l[j] = f2bf(v[j] - bf2f(hh));
  }
  reinterpret_cast<u16x4*>(hi)[i] = h;
  reinterpret_cast<u16x4*>(lo)[i] = l;
}

// ---------------- projection: Y = X * W^T (split-bf16, 3-pass MFMA) ----------------
// X: [16384][512] fp32 (converted to hi/lo on the fly)
// Whi/Wlo: [512][512] bf16 bits
// transpose_out==0: Yhi/Ylo at [row][col] ([16384][512])
// transpose_out==1: Yhi/Ylo at [b][col][n] ([8][512][2048])  (for V^T)
__global__ __launch_bounds__(256) void proj_k(
    const float* __restrict__ X,
    const unsigned short* __restrict__ Whi, const unsigned short* __restrict__ Wlo,
    unsigned short* __restrict__ Yhi, unsigned short* __restrict__ Ylo,
    int transpose_out)
{
  const int mbase = blockIdx.x * 64;
  const int nbase = blockIdx.y * 64;
  const int tid = threadIdx.x;
  const int w = tid >> 6, lane = tid & 63;
  const int l15 = lane & 15, l4 = lane >> 4;

  f32x4 acc[4];
  #pragma unroll
  for (int c=0;c<4;c++) acc[c] = (f32x4){0.f,0.f,0.f,0.f};

  const int arow = mbase + w*16 + l15;
  const float* xp = X + (size_t)arow * DD + l4*8;

  #pragma unroll
  for (int kc = 0; kc < 16; ++kc) {
    f32x4 xa = *reinterpret_cast<const f32x4*>(xp + kc*32);
    f32x4 xb = *reinterpret_cast<const f32x4*>(xp + kc*32 + 4);
    short8 ahi, alo;
    #pragma unroll
    for (int j=0;j<4;j++){
      unsigned short h0 = f2bf(xa[j]);
      ahi[j]   = (short)h0;  alo[j]   = (short)f2bf(xa[j]-bf2f(h0));
      unsigned short h1 = f2bf(xb[j]);
      ahi[4+j] = (short)h1;  alo[4+j] = (short)f2bf(xb[j]-bf2f(h1));
    }
    short8 bhi[4], blo[4];
    #pragma unroll
    for (int c=0;c<4;c++){
      const size_t brow = (size_t)(nbase + c*16 + l15);
      bhi[c] = *reinterpret_cast<const short8*>(Whi + brow*DD + kc*32 + l4*8);
      blo[c] = *reinterpret_cast<const short8*>(Wlo + brow*DD + kc*32 + l4*8);
    }
    #pragma unroll
    for (int c=0;c<4;c++) acc[c] = __builtin_amdgcn_mfma_f32_16x16x32_bf16(ahi, bhi[c], acc[c], 0,0,0);
    #pragma unroll
    for (int c=0;c<4;c++) acc[c] = __builtin_amdgcn_mfma_f32_16x16x32_bf16(ahi, blo[c], acc[c], 0,0,0);
    #pragma unroll
    for (int c=0;c<4;c++) acc[c] = __builtin_amdgcn_mfma_f32_16x16x32_bf16(alo, bhi[c], acc[c], 0,0,0);
  }

  #pragma unroll
  for (int c=0;c<4;c++){
    #pragma unroll
    for (int j=0;j<4;j++){
      const int row = mbase + w*16 + l4*4 + j;
      const int col = nbase + c*16 + l15;
      const float y = acc[c][j];
      const unsigned short h = f2bf(y);
      const unsigned short l = f2bf(y - bf2f(h));
      size_t idx;
      if (!transpose_out) idx = (size_t)row*DD + col;
      else {
        const int bb = row >> 11, n = row & 2047;
        idx = ((size_t)(bb*DD + col))*NKL + n;
      }
      Yhi[idx] = h; Ylo[idx] = l;
    }
  }
}

// ---------------- fused flash attention (split-bf16, 3-pass MFMA) ----------------
// Grid: 256 blocks (b = bid&7 for XCD locality, qt = bid>>3), 512 threads (8 waves).
// QB=64, KB=32. Q frags in registers, O (64x512 fp32) in registers.
__global__ __launch_bounds__(512, 2) void attn_k(
    const unsigned short* __restrict__ Qhi, const unsigned short* __restrict__ Qlo,
    const unsigned short* __restrict__ Khi, const unsigned short* __restrict__ Klo,
    const unsigned short* __restrict__ Vthi, const unsigned short* __restrict__ Vtlo,
    float* __restrict__ Out)
{
  __shared__ __align__(16) float S_lds[64][33];
  __shared__ __align__(16) unsigned short Phi_s[64][40];
  __shared__ __align__(16) unsigned short Plo_s[64][40];
  __shared__ float m_s[64], l_s[64], sc_s[64];

  const int bid = blockIdx.x;
  const int b  = bid & 7;
  const int qt = bid >> 3;
  const int tid = threadIdx.x;
  const int w = tid >> 6, lane = tid & 63;
  const int l15 = lane & 15, l4 = lane >> 4;
  const int rw = w & 3,  cw = w >> 2;   // S-fragment: rows rw*16.., cols cw*16..
  const int orw = w >> 2, ocw = w & 3;  // O: rows orw*32.., cols ocw*128..

  // Q fragments (this wave's 16 S-rows, full K=512, hi+lo) in registers: 128 VGPRs
  short8 qhf[16], qlf[16];
  {
    const size_t qoff = (size_t)(b*NQL + qt*64 + rw*16 + l15)*DD + l4*8;
    #pragma unroll
    for (int kc=0;kc<16;kc++){
      qhf[kc] = *reinterpret_cast<const short8*>(Qhi + qoff + kc*32);
      qlf[kc] = *reinterpret_cast<const short8*>(Qlo + qoff + kc*32);
    }
  }

  f32x4 o[2][8];
  #pragma unroll
  for (int i=0;i<2;i++)
    #pragma unroll
    for (int j=0;j<8;j++) o[i][j] = (f32x4){0.f,0.f,0.f,0.f};

  if (tid < 64){ m_s[tid] = -1e30f; l_s[tid] = 0.f; }
  __syncthreads();

  for (int kt=0; kt<64; ++kt){
    // ---- S = Q K^T  (this wave's 16x16 fragment), 3 independent acc chains ----
    f32x4 shh = (f32x4){0.f,0.f,0.f,0.f};
    f32x4 shl = (f32x4){0.f,0.f,0.f,0.f};
    f32x4 slh = (f32x4){0.f,0.f,0.f,0.f};
    const size_t koff = (size_t)(b*NKL + kt*32 + cw*16 + l15)*DD + l4*8;
    #pragma unroll
    for (int kc=0;kc<16;kc++){
      const short8 kh = *reinterpret_cast<const short8*>(Khi + koff + kc*32);
      const short8 kl = *reinterpret_cast<const short8*>(Klo + koff + kc*32);
      shh = __builtin_amdgcn_mfma_f32_16x16x32_bf16(qhf[kc], kh, shh, 0,0,0);
      shl = __builtin_amdgcn_mfma_f32_16x16x32_bf16(qhf[kc], kl, shl, 0,0,0);
      slh = __builtin_amdgcn_mfma_f32_16x16x32_bf16(qlf[kc], kh, slh, 0,0,0);
    }
    const f32x4 sv = shh + shl + slh;
    #pragma unroll
    for (int j=0;j<4;j++) S_lds[rw*16 + l4*4 + j][cw*16 + l15] = sv[j];
    __syncthreads();

    // ---- online softmax (8 threads per row) ----
    {
      const int row = tid >> 3, sub = tid & 7;
      const float v0=S_lds[row][sub*4+0], v1=S_lds[row][sub*4+1];
      const float v2=S_lds[row][sub*4+2], v3=S_lds[row][sub*4+3];
      float mx = fmaxf(fmaxf(v0,v1), fmaxf(v2,v3));
      mx = fmaxf(mx, __shfl_xor(mx, 1, 64));
      mx = fmaxf(mx, __shfl_xor(mx, 2, 64));
      mx = fmaxf(mx, __shfl_xor(mx, 4, 64));
      const float m_old = m_s[row];
      const float m_new = fmaxf(m_old, mx);
      const float p0=__expf(v0-m_new), p1=__expf(v1-m_new);
      const float p2=__expf(v2-m_new), p3=__expf(v3-m_new);
      float sm = p0+p1+p2+p3;
      sm += __shfl_xor(sm,1,64); sm += __shfl_xor(sm,2,64); sm += __shfl_xor(sm,4,64);
      if (sub==0){
        const float sc = __expf(m_old - m_new);
        sc_s[row] = sc;
        l_s[row] = l_s[row]*sc + sm;
        m_s[row] = m_new;
      }
      unsigned short h;
      h=f2bf(p0); Phi_s[row][sub*4+0]=h; Plo_s[row][sub*4+0]=f2bf(p0-bf2f(h));
      h=f2bf(p1); Phi_s[row][sub*4+1]=h; Plo_s[row][sub*4+1]=f2bf(p1-bf2f(h));
      h=f2bf(p2); Phi_s[row][sub*4+2]=h; Plo_s[row][sub*4+2]=f2bf(p2-bf2f(h));
      h=f2bf(p3); Phi_s[row][sub*4+3]=h; Plo_s[row][sub*4+3]=f2bf(p3-bf2f(h));
    }
    __syncthreads();

    // ---- rescale O (skip when running max unchanged — common with peaked logits) ----
    {
      float scs[2][4];
      bool need = false;
      #pragma unroll
      for (int pr=0; pr<2; pr++)
        #pragma unroll
        for (int j=0;j<4;j++){
          const float s0 = sc_s[orw*32 + pr*16 + l4*4 + j];
          scs[pr][j] = s0;
          need = need || (s0 < 0.999999f);
        }
      if (__any(need)){
        #pragma unroll
        for (int pr=0;pr<2;pr++)
          #pragma unroll
          for (int c=0;c<8;c++)
            #pragma unroll
            for (int j=0;j<4;j++) o[pr][c][j] *= scs[pr][j];
      }
    }

    // ---- O += P V  (A = P rows from LDS, B = Vt rows from global) ----
    short8 pah[2], pal[2];
    #pragma unroll
    for (int pr=0;pr<2;pr++){
      const int prow = orw*32 + pr*16 + l15;
      pah[pr] = *reinterpret_cast<const short8*>(&Phi_s[prow][l4*8]);
      pal[pr] = *reinterpret_cast<const short8*>(&Plo_s[prow][l4*8]);
    }
    #pragma unroll
    for (int chf=0; chf<2; ++chf){
      short8 vh[4], vl[4];
      #pragma unroll
      for (int c=0;c<4;c++){
        const int dcol = ocw*128 + (chf*4+c)*16 + l15;
        const size_t vidx = ((size_t)(b*DD + dcol))*NKL + kt*32 + l4*8;
        vh[c] = *reinterpret_cast<const short8*>(Vthi + vidx);
        vl[c] = *reinterpret_cast<const short8*>(Vtlo + vidx);
      }
      #pragma unroll
      for (int pr=0;pr<2;pr++)
        #pragma unroll
        for (int c=0;c<4;c++)
          o[pr][chf*4+c] = __builtin_amdgcn_mfma_f32_16x16x32_bf16(pah[pr], vh[c], o[pr][chf*4+c], 0,0,0);
      #pragma unroll
      for (int pr=0;pr<2;pr++)
        #pragma unroll
        for (int c=0;c<4;c++)
          o[pr][chf*4+c] = __builtin_amdgcn_mfma_f32_16x16x32_bf16(pah[pr], vl[c], o[pr][chf*4+c], 0,0,0);
      #pragma unroll
      for (int pr=0;pr<2;pr++)
        #pragma unroll
        for (int c=0;c<4;c++)
          o[pr][chf*4+c] = __builtin_amdgcn_mfma_f32_16x16x32_bf16(pal[pr], vh[c], o[pr][chf*4+c], 0,0,0);
    }
    // no barrier needed here: next iteration's first barrier orders reuse
  }

  // ---- epilogue: O /= l, store fp32 ----
  #pragma unroll
  for (int pr=0;pr<2;pr++){
    #pragma unroll
    for (int j=0;j<4;j++){
      const int row = orw*32 + pr*16 + l4*4 + j;
      const float inv = 1.0f / l_s[row];
      const size_t obase = (size_t)(b*NQL + qt*64 + row)*DD;
      #pragma unroll
      for (int c=0;c<8;c++){
        const int col = ocw*128 + c*16 + l15;
        Out[obase + col] = o[pr][c][j]*inv;
      }
    }
  }
}

extern "C" void kernel_launch(void* const* d_in, const int* in_sizes, int n_in,
                              void* d_out, int out_size, void* d_ws, size_t ws_size,
                              hipStream_t stream) {
  const float* query = (const float*)d_in[0];
  const float* key   = (const float*)d_in[1];
  const float* value = (const float*)d_in[2];
  const float* Wq    = (const float*)d_in[3];
  const float* Wk    = (const float*)d_in[4];
  const float* Wv    = (const float*)d_in[5];
  float* out = (float*)d_out;

  const size_t SB = (size_t)NB*NQL*DD;   // 8,388,608 elems
  const size_t WB = (size_t)DD*DD;       //   262,144 elems

  unsigned short* p = (unsigned short*)d_ws;
  unsigned short *wqh = p,        *wql = p +   WB;
  unsigned short *wkh = p + 2*WB, *wkl = p + 3*WB;
  unsigned short *wvh = p + 4*WB, *wvl = p + 5*WB;
  unsigned short* q0 = p + 6*WB;
  unsigned short *qh  = q0,        *ql  = q0 +   SB;
  unsigned short *kh  = q0 + 2*SB, *kl  = q0 + 3*SB;
  unsigned short *vth = q0 + 4*SB, *vtl = q0 + 5*SB;

  split_k<<<256, 256, 0, stream>>>(Wq, wqh, wql, (int)(WB/4));
  split_k<<<256, 256, 0, stream>>>(Wk, wkh, wkl, (int)(WB/4));
  split_k<<<256, 256, 0, stream>>>(Wv, wvh, wvl, (int)(WB/4));

  dim3 pg(256, 8);
  proj_k<<<pg, 256, 0, stream>>>(query, wqh, wql, qh,  ql,  0);
  proj_k<<<pg, 256, 0, stream>>>(key,   wkh, wkl, kh,  kl,  0);
  proj_k<<<pg, 256, 0, stream>>>(value, wvh, wvl, vth, vtl, 1);

  attn_k<<<256, 512, 0, stream>>>(qh, ql, kh, kl, vth, vtl, out);
}

// Round 2
// 694.834 us; speedup vs baseline: 1.9224x; 1.9224x over previous
//
#include <hip/hip_runtime.h>

typedef __attribute__((ext_vector_type(8))) short short8;
typedef __attribute__((ext_vector_type(4))) float f32x4;
typedef __attribute__((ext_vector_type(4))) unsigned short u16x4;

#define NB 8
#define NQL 2048
#define NKL 2048
#define DD 512

static __device__ __forceinline__ unsigned short f2bf(float x){
  unsigned u = __builtin_bit_cast(unsigned, x);
  unsigned r = u + 0x7FFFu + ((u >> 16) & 1u);
  return (unsigned short)(r >> 16);
}
static __device__ __forceinline__ float bf2f(unsigned short h){
  unsigned u = ((unsigned)h) << 16;
  return __builtin_bit_cast(float, u);
}

static __device__ __forceinline__ void stage16(const unsigned short* g, unsigned short* l){
  __builtin_amdgcn_global_load_lds(
      (const __attribute__((address_space(1))) void*)g,
      (__attribute__((address_space(3))) void*)l, 16, 0, 0);
}

static __device__ __forceinline__ void barrier_lgkm(){
  asm volatile("s_waitcnt lgkmcnt(0)" ::: "memory");
  __builtin_amdgcn_s_barrier();
  asm volatile("" ::: "memory");
}

// ---------------- split fp32 -> bf16 hi/lo ----------------
__global__ __launch_bounds__(256) void split_k(const float* __restrict__ x,
    unsigned short* __restrict__ hi, unsigned short* __restrict__ lo, int n4){
  int i = blockIdx.x*256 + threadIdx.x;
  if (i >= n4) return;
  f32x4 v = reinterpret_cast<const f32x4*>(x)[i];
  u16x4 h, l;
  #pragma unroll
  for (int j=0;j<4;j++){
    unsigned short hh = f2bf(v[j]);
    h[j] = hh;
    l[j] = f2bf(v[j] - bf2f(hh));
  }
  reinterpret_cast<u16x4*>(hi)[i] = h;
  reinterpret_cast<u16x4*>(lo)[i] = l;
}

// ---------------- projection: Y = X * W^T (split-bf16, 3-pass MFMA) ----------------
// mode 0: Q  -> Yhi/Ylo separate arrays [16384][512]
// mode 1: K  -> single array, per-tile [b][kt][2(hi/lo)][32][512], cg XOR-swizzled by (row&7)
// mode 2: V  -> single array, per-tile [b][kt][2(hi/lo)][512][32], k-slot swizzled by ((dcol>>1)&3)
__global__ __launch_bounds__(256) void proj_k(
    const float* __restrict__ X,
    const unsigned short* __restrict__ Whi, const unsigned short* __restrict__ Wlo,
    unsigned short* __restrict__ Yhi, unsigned short* __restrict__ Ylo,
    int mode)
{
  const int mbase = blockIdx.x * 64;
  const int nbase = blockIdx.y * 64;
  const int tid = threadIdx.x;
  const int w = tid >> 6, lane = tid & 63;
  const int l15 = lane & 15, l4 = lane >> 4;

  f32x4 acc[4];
  #pragma unroll
  for (int c=0;c<4;c++) acc[c] = (f32x4){0.f,0.f,0.f,0.f};

  const int arow = mbase + w*16 + l15;
  const float* xp = X + (size_t)arow * DD + l4*8;

  #pragma unroll
  for (int kc = 0; kc < 16; ++kc) {
    f32x4 xa = *reinterpret_cast<const f32x4*>(xp + kc*32);
    f32x4 xb = *reinterpret_cast<const f32x4*>(xp + kc*32 + 4);
    short8 ahi, alo;
    #pragma unroll
    for (int j=0;j<4;j++){
      unsigned short h0 = f2bf(xa[j]);
      ahi[j]   = (short)h0;  alo[j]   = (short)f2bf(xa[j]-bf2f(h0));
      unsigned short h1 = f2bf(xb[j]);
      ahi[4+j] = (short)h1;  alo[4+j] = (short)f2bf(xb[j]-bf2f(h1));
    }
    short8 bhi[4], blo[4];
    #pragma unroll
    for (int c=0;c<4;c++){
      const size_t brow = (size_t)(nbase + c*16 + l15);
      bhi[c] = *reinterpret_cast<const short8*>(Whi + brow*DD + kc*32 + l4*8);
      blo[c] = *reinterpret_cast<const short8*>(Wlo + brow*DD + kc*32 + l4*8);
    }
    #pragma unroll
    for (int c=0;c<4;c++) acc[c] = __builtin_amdgcn_mfma_f32_16x16x32_bf16(ahi, bhi[c], acc[c], 0,0,0);
    #pragma unroll
    for (int c=0;c<4;c++) acc[c] = __builtin_amdgcn_mfma_f32_16x16x32_bf16(ahi, blo[c], acc[c], 0,0,0);
    #pragma unroll
    for (int c=0;c<4;c++) acc[c] = __builtin_amdgcn_mfma_f32_16x16x32_bf16(alo, bhi[c], acc[c], 0,0,0);
  }

  #pragma unroll
  for (int c=0;c<4;c++){
    #pragma unroll
    for (int j=0;j<4;j++){
      const int row = mbase + w*16 + l4*4 + j;
      const int col = nbase + c*16 + l15;
      const float y = acc[c][j];
      const unsigned short h = f2bf(y);
      const unsigned short l = f2bf(y - bf2f(h));
      size_t idxH, idxL;
      if (mode == 0){
        idxH = idxL = (size_t)row*DD + col;
      } else {
        const int bb = row >> 11, n = row & 2047, kt = n >> 5;
        const size_t tb = ((size_t)(bb*64 + kt)) << 15;  // 32768 elems/tile
        if (mode == 1){
          const int kr = n & 31, cg = col >> 3, ci = col & 7;
          idxH = tb + ((size_t)kr)*512 + (size_t)((((cg ^ (kr & 7)) << 3)) | ci);
        } else {
          const int kk = n & 31;
          idxH = tb + ((size_t)col)*32 + (size_t)(((((kk >> 3) ^ ((col >> 1) & 3)) << 3)) | (kk & 7));
        }
        idxL = idxH + 16384;
      }
      Yhi[idxH] = h; Ylo[idxL] = l;
    }
  }
}

// ---------------- fused flash attention (split-bf16, LDS-staged, pipelined) ----------------
// Grid: 256 blocks (b = bid&7 for XCD locality, qt = bid>>3), 512 threads (8 waves).
// QB=64, KB=32. Q frags in registers, O (64x512 fp32) in registers.
// K(kt+1) and V(kt) staged via global_load_lds with counted vmcnt(8); raw s_barrier.
__global__ __launch_bounds__(512, 2) void attn_k(
    const unsigned short* __restrict__ Qhi, const unsigned short* __restrict__ Qlo,
    const unsigned short* __restrict__ Kt,  const unsigned short* __restrict__ Vt,
    float* __restrict__ Out)
{
  __shared__ unsigned short K_lds[2][32][512];   // 64 KB  (hi/lo, row, col cg^(row&7) swizzled)
  __shared__ unsigned short V_lds[2][512][32];   // 64 KB  (hi/lo, dcol, slot l4^((dcol>>1)&3) swizzled)
  __shared__ float S_lds[64][33];                // 8448 B
  __shared__ unsigned short Phi_s[64][40];
  __shared__ unsigned short Plo_s[64][40];       // 10240 B
  __shared__ float m_s[64], l_s[64], sc_s[64];

  const int bid = blockIdx.x;
  const int b  = bid & 7;
  const int qt = bid >> 3;
  const int tid = threadIdx.x;
  const int w = tid >> 6, lane = tid & 63;
  const int l15 = lane & 15, l4 = lane >> 4;
  const int rw = w & 3,  cw = w >> 2;   // S-fragment: rows rw*16.., cols cw*16..
  const int orw = w >> 2, ocw = w & 3;  // O: rows orw*32.., cols ocw*128..

  // Q fragments (this wave's 16 S-rows, full K=512, hi+lo) in registers
  short8 qhf[16], qlf[16];
  {
    const size_t qoff = (size_t)(b*NQL + qt*64 + rw*16 + l15)*DD + l4*8;
    #pragma unroll
    for (int kc=0;kc<16;kc++){
      qhf[kc] = *reinterpret_cast<const short8*>(Qhi + qoff + kc*32);
      qlf[kc] = *reinterpret_cast<const short8*>(Qlo + qoff + kc*32);
    }
  }

  f32x4 o[2][8];
  #pragma unroll
  for (int i=0;i<2;i++)
    #pragma unroll
    for (int j=0;j<8;j++) o[i][j] = (f32x4){0.f,0.f,0.f,0.f};

  if (tid < 64){ m_s[tid] = -1e30f; l_s[tid] = 0.f; }

  const unsigned short* gK = Kt + ((size_t)(b*64) << 15);
  const unsigned short* gV = Vt + ((size_t)(b*64) << 15);
  unsigned short* lK = &K_lds[0][0][0];
  unsigned short* lV = &V_lds[0][0][0];
  const int goff  = w*512 + lane*8;   // elems
  const int lbase = w*512;            // elems (wave-uniform LDS base)

  // prologue: stage K tile 0 (8 issues/thread, 64 KB)
  #pragma unroll
  for (int r=0;r<8;r++) stage16(gK + r*4096 + goff, lK + r*4096 + lbase);

  const int krow = cw*16 + l15;
  const int kx = krow & 7;

  #pragma unroll 1
  for (int kt=0; kt<64; ++kt){
    // ---- stage V(kt) (outstanding: K(kt)=8 older, V(kt)=8) ----
    {
      const unsigned short* g = gV + ((size_t)kt << 15);
      #pragma unroll
      for (int r=0;r<8;r++) stage16(g + r*4096 + goff, lV + r*4096 + lbase);
    }
    asm volatile("s_waitcnt vmcnt(8)" ::: "memory");   // K(kt) resident
    barrier_lgkm();

    // ---- S = Q K^T from K_lds (3-pass) ----
    f32x4 shh = (f32x4){0.f,0.f,0.f,0.f};
    f32x4 shl = (f32x4){0.f,0.f,0.f,0.f};
    f32x4 slh = (f32x4){0.f,0.f,0.f,0.f};
    #pragma unroll
    for (int kc=0;kc<16;kc++){
      const int cg = ((kc*4 + l4) ^ kx) << 3;
      const short8 kh = *reinterpret_cast<const short8*>(&K_lds[0][krow][cg]);
      const short8 kl = *reinterpret_cast<const short8*>(&K_lds[1][krow][cg]);
      shh = __builtin_amdgcn_mfma_f32_16x16x32_bf16(qhf[kc], kh, shh, 0,0,0);
      shl = __builtin_amdgcn_mfma_f32_16x16x32_bf16(qhf[kc], kl, shl, 0,0,0);
      slh = __builtin_amdgcn_mfma_f32_16x16x32_bf16(qlf[kc], kh, slh, 0,0,0);
    }
    const f32x4 sv = shh + shl + slh;
    #pragma unroll
    for (int j=0;j<4;j++) S_lds[rw*16 + l4*4 + j][cw*16 + l15] = sv[j];
    barrier_lgkm();

    // ---- online softmax (8 threads per row) ----
    {
      const int row = tid >> 3, sub = tid & 7;
      const float v0=S_lds[row][sub*4+0], v1=S_lds[row][sub*4+1];
      const float v2=S_lds[row][sub*4+2], v3=S_lds[row][sub*4+3];
      float mx = fmaxf(fmaxf(v0,v1), fmaxf(v2,v3));
      mx = fmaxf(mx, __shfl_xor(mx, 1, 64));
      mx = fmaxf(mx, __shfl_xor(mx, 2, 64));
      mx = fmaxf(mx, __shfl_xor(mx, 4, 64));
      const float m_old = m_s[row];
      const float m_new = fmaxf(m_old, mx);
      const float p0=__expf(v0-m_new), p1=__expf(v1-m_new);
      const float p2=__expf(v2-m_new), p3=__expf(v3-m_new);
      float sm = p0+p1+p2+p3;
      sm += __shfl_xor(sm,1,64); sm += __shfl_xor(sm,2,64); sm += __shfl_xor(sm,4,64);
      if (sub==0){
        const float sc = __expf(m_old - m_new);
        sc_s[row] = sc;
        l_s[row] = l_s[row]*sc + sm;
        m_s[row] = m_new;
      }
      unsigned short h;
      h=f2bf(p0); Phi_s[row][sub*4+0]=h; Plo_s[row][sub*4+0]=f2bf(p0-bf2f(h));
      h=f2bf(p1); Phi_s[row][sub*4+1]=h; Plo_s[row][sub*4+1]=f2bf(p1-bf2f(h));
      h=f2bf(p2); Phi_s[row][sub*4+2]=h; Plo_s[row][sub*4+2]=f2bf(p2-bf2f(h));
      h=f2bf(p3); Phi_s[row][sub*4+3]=h; Plo_s[row][sub*4+3]=f2bf(p3-bf2f(h));
    }
    barrier_lgkm();

    // ---- stage K(kt+1) (K_lds free: all K reads completed before S barrier) ----
    {
      const unsigned short* g = gK + ((size_t)((kt+1)&63) << 15);
      #pragma unroll
      for (int r=0;r<8;r++) stage16(g + r*4096 + goff, lK + r*4096 + lbase);
    }
    asm volatile("s_waitcnt vmcnt(8)" ::: "memory");   // V(kt) resident
    barrier_lgkm();

    // ---- rescale O (skip when running max unchanged) ----
    {
      float scs[2][4];
      bool need = false;
      #pragma unroll
      for (int pr=0; pr<2; pr++)
        #pragma unroll
        for (int j=0;j<4;j++){
          const float s0 = sc_s[orw*32 + pr*16 + l4*4 + j];
          scs[pr][j] = s0;
          need = need || (s0 < 0.999999f);
        }
      if (__any(need)){
        #pragma unroll
        for (int pr=0;pr<2;pr++)
          #pragma unroll
          for (int c=0;c<8;c++)
            #pragma unroll
            for (int j=0;j<4;j++) o[pr][c][j] *= scs[pr][j];
      }
    }

    // ---- O += P V  (A = P rows from LDS, B = V rows from V_lds) ----
    short8 pah[2], pal[2];
    #pragma unroll
    for (int pr=0;pr<2;pr++){
      const int prow = orw*32 + pr*16 + l15;
      pah[pr] = *reinterpret_cast<const short8*>(&Phi_s[prow][l4*8]);
      pal[pr] = *reinterpret_cast<const short8*>(&Plo_s[prow][l4*8]);
    }
    #pragma unroll
    for (int cc=0; cc<8; ++cc){
      const int dcol = ocw*128 + cc*16 + l15;
      const int vb = (l4 ^ ((dcol>>1)&3)) << 3;
      const short8 vh = *reinterpret_cast<const short8*>(&V_lds[0][dcol][vb]);
      const short8 vl = *reinterpret_cast<const short8*>(&V_lds[1][dcol][vb]);
      o[0][cc] = __builtin_amdgcn_mfma_f32_16x16x32_bf16(pah[0], vh, o[0][cc], 0,0,0);
      o[1][cc] = __builtin_amdgcn_mfma_f32_16x16x32_bf16(pah[1], vh, o[1][cc], 0,0,0);
      o[0][cc] = __builtin_amdgcn_mfma_f32_16x16x32_bf16(pal[0], vh, o[0][cc], 0,0,0);
      o[1][cc] = __builtin_amdgcn_mfma_f32_16x16x32_bf16(pal[1], vh, o[1][cc], 0,0,0);
      o[0][cc] = __builtin_amdgcn_mfma_f32_16x16x32_bf16(pah[0], vl, o[0][cc], 0,0,0);
      o[1][cc] = __builtin_amdgcn_mfma_f32_16x16x32_bf16(pah[1], vl, o[1][cc], 0,0,0);
    }
    barrier_lgkm();   // V_lds / P_lds reads done -> reusable next iter
  }

  // ---- epilogue: O /= l, store fp32 ----
  #pragma unroll
  for (int pr=0;pr<2;pr++){
    #pragma unroll
    for (int j=0;j<4;j++){
      const int row = orw*32 + pr*16 + l4*4 + j;
      const float inv = 1.0f / l_s[row];
      const size_t obase = (size_t)(b*NQL + qt*64 + row)*DD;
      #pragma unroll
      for (int c=0;c<8;c++){
        const int col = ocw*128 + c*16 + l15;
        Out[obase + col] = o[pr][c][j]*inv;
      }
    }
  }
}

extern "C" void kernel_launch(void* const* d_in, const int* in_sizes, int n_in,
                              void* d_out, int out_size, void* d_ws, size_t ws_size,
                              hipStream_t stream) {
  const float* query = (const float*)d_in[0];
  const float* key   = (const float*)d_in[1];
  const float* value = (const float*)d_in[2];
  const float* Wq    = (const float*)d_in[3];
  const float* Wk    = (const float*)d_in[4];
  const float* Wv    = (const float*)d_in[5];
  float* out = (float*)d_out;

  const size_t SB = (size_t)NB*NQL*DD;   // 8,388,608 elems
  const size_t WB = (size_t)DD*DD;       //   262,144 elems

  unsigned short* p = (unsigned short*)d_ws;
  unsigned short *wqh = p,        *wql = p +   WB;
  unsigned short *wkh = p + 2*WB, *wkl = p + 3*WB;
  unsigned short *wvh = p + 4*WB, *wvl = p + 5*WB;
  unsigned short* q0 = p + 6*WB;
  unsigned short *qh  = q0,        *ql  = q0 + SB;
  unsigned short *Ktl = q0 + 2*SB;            // [8][64][2][32][512]  = 2*SB elems
  unsigned short *Vtl = q0 + 4*SB;            // [8][64][2][512][32]  = 2*SB elems

  split_k<<<256, 256, 0, stream>>>(Wq, wqh, wql, (int)(WB/4));
  split_k<<<256, 256, 0, stream>>>(Wk, wkh, wkl, (int)(WB/4));
  split_k<<<256, 256, 0, stream>>>(Wv, wvh, wvl, (int)(WB/4));

  dim3 pg(256, 8);
  proj_k<<<pg, 256, 0, stream>>>(query, wqh, wql, qh,  ql,  0);
  proj_k<<<pg, 256, 0, stream>>>(key,   wkh, wkl, Ktl, Ktl, 1);
  proj_k<<<pg, 256, 0, stream>>>(value, wvh, wvl, Vtl, Vtl, 2);

  attn_k<<<256, 512, 0, stream>>>(qh, ql, Ktl, Vtl, out);
}

// Round 3
// 361.731 us; speedup vs baseline: 3.6927x; 1.9209x over previous
//
#include <hip/hip_runtime.h>

typedef __attribute__((ext_vector_type(8))) short short8;
typedef __attribute__((ext_vector_type(4))) float f32x4;
typedef __attribute__((ext_vector_type(4))) unsigned short u16x4;

#define NB 8
#define NQL 2048
#define NKL 2048
#define DD 512

static __device__ __forceinline__ unsigned short f2bf(float x){
  unsigned u = __builtin_bit_cast(unsigned, x);
  unsigned r = u + 0x7FFFu + ((u >> 16) & 1u);
  return (unsigned short)(r >> 16);
}
static __device__ __forceinline__ float bf2f(unsigned short h){
  unsigned u = ((unsigned)h) << 16;
  return __builtin_bit_cast(float, u);
}

static __device__ __forceinline__ void stage16(const unsigned short* g, unsigned short* l){
  __builtin_amdgcn_global_load_lds(
      (const __attribute__((address_space(1))) void*)g,
      (__attribute__((address_space(3))) void*)l, 16, 0, 0);
}

static __device__ __forceinline__ void barrier_lgkm(){
  asm volatile("s_waitcnt lgkmcnt(0)" ::: "memory");
  __builtin_amdgcn_s_barrier();
  asm volatile("" ::: "memory");
}

// ---------------- split fp32 -> bf16 hi/lo (W matrices only) ----------------
__global__ __launch_bounds__(256) void split_k(const float* __restrict__ x,
    unsigned short* __restrict__ hi, unsigned short* __restrict__ lo, int n4){
  int i = blockIdx.x*256 + threadIdx.x;
  if (i >= n4) return;
  f32x4 v = reinterpret_cast<const f32x4*>(x)[i];
  u16x4 h, l;
  #pragma unroll
  for (int j=0;j<4;j++){
    unsigned short hh = f2bf(v[j]);
    h[j] = hh;
    l[j] = f2bf(v[j] - bf2f(hh));
  }
  reinterpret_cast<u16x4*>(hi)[i] = h;
  reinterpret_cast<u16x4*>(lo)[i] = l;
}

// ---------------- fused projections: Y = X * W^T (128x128 tile, staged, dbuf) ----------------
// grid (128, 4, 3): x = M-block (16384/128), y = N-block (512/128), z = {Q,K,V}
// LDS AB[buf][which][128][32], which: 0=Ah 1=Al 2=Bh 3=Bl. XOR swizzle cg' = cg ^ ((row>>1)&3).
// z=0: out flat hi/lo [16384][512]
// z=1: out K tiles [b][kt][2][32][512], col-group ^ (row&7)
// z=2: out V tiles [b][kt][2][512][32], k-slot ^ ((dcol>>1)&3)
__global__ __launch_bounds__(256, 2) void proj2_k(
    const float* __restrict__ Xq, const float* __restrict__ Xk, const float* __restrict__ Xv,
    const unsigned short* __restrict__ Wqh, const unsigned short* __restrict__ Wql,
    const unsigned short* __restrict__ Wkh, const unsigned short* __restrict__ Wkl,
    const unsigned short* __restrict__ Wvh, const unsigned short* __restrict__ Wvl,
    unsigned short* __restrict__ Yqh, unsigned short* __restrict__ Yql,
    unsigned short* __restrict__ Ykt, unsigned short* __restrict__ Yvt)
{
  __shared__ unsigned short AB[2][4][128][32];   // 64 KB

  const int z = blockIdx.z;
  const float* X          = (z==0) ? Xq  : (z==1) ? Xk  : Xv;
  const unsigned short* Wh = (z==0) ? Wqh : (z==1) ? Wkh : Wvh;
  const unsigned short* Wl = (z==0) ? Wql : (z==1) ? Wkl : Wvl;

  const int mbase = blockIdx.x * 128;
  const int nbase = blockIdx.y * 128;
  const int tid = threadIdx.x;
  const int w = tid >> 6, lane = tid & 63;
  const int l15 = lane & 15, l4 = lane >> 4;
  const int wr = w >> 1, wc = w & 1;

  // A reg-stage mapping: thread -> (row, half)
  const int arow = tid >> 1, ahalf = tid & 1;
  // B gload_lds mapping per round r: row = r*64 + w*16 + (lane>>2), kg = (lane&3)^((lane>>3)&3)
  const int brow_l = w*16 + (lane>>2);
  const int bkg    = (lane & 3) ^ ((lane >> 3) & 3);

  f32x4 acc[4][4];
  #pragma unroll
  for (int m=0;m<4;m++)
    #pragma unroll
    for (int n=0;n<4;n++) acc[m][n] = (f32x4){0.f,0.f,0.f,0.f};

  // ---- prologue: load A(0) to regs, issue B(0) gload_lds ----
  f32x4 xa[4];
  {
    const f32x4* xp = reinterpret_cast<const f32x4*>(X + (size_t)(mbase+arow)*DD + ahalf*16);
    #pragma unroll
    for (int q=0;q<4;q++) xa[q] = xp[q];
  }
  {
    unsigned short* lB = &AB[0][2][0][0] + w*512;
    #pragma unroll
    for (int r=0;r<2;r++){
      const size_t gh = (size_t)(nbase + r*64 + brow_l)*DD + bkg*8;
      stage16(Wh + gh, lB + r*2048);
      stage16(Wl + gh, lB + 4096 + r*2048);
    }
  }
  // convert+write A(0)
  {
    asm volatile("s_waitcnt vmcnt(4)" ::: "memory");
    short8 h0,h1,l0,l1;
    #pragma unroll
    for (int q=0;q<2;q++){
      #pragma unroll
      for (int j=0;j<4;j++){
        float v0 = xa[q*2][j], v1 = xa[q*2+1][j];
        unsigned short a = f2bf(v0); unsigned short b = f2bf(v1);
        if (q==0){ h0[j]=(short)a; h0[4+j]=(short)b; l0[j]=(short)f2bf(v0-bf2f(a)); l0[4+j]=(short)f2bf(v1-bf2f(b)); }
        else     { h1[j]=(short)a; h1[4+j]=(short)b; l1[j]=(short)f2bf(v0-bf2f(a)); l1[4+j]=(short)f2bf(v1-bf2f(b)); }
      }
    }
    const int sw = (arow>>1)&3;
    const int cg0 = (ahalf*2) ^ sw, cg1 = (ahalf*2+1) ^ sw;
    *reinterpret_cast<short8*>(&AB[0][0][arow][cg0*8]) = h0;
    *reinterpret_cast<short8*>(&AB[0][0][arow][cg1*8]) = h1;
    *reinterpret_cast<short8*>(&AB[0][1][arow][cg0*8]) = l0;
    *reinterpret_cast<short8*>(&AB[0][1][arow][cg1*8]) = l1;
  }

  const int asw = (l15>>1)&3;

  #pragma unroll 1
  for (int s=0; s<16; ++s){
    const int cur = s&1, nxt = cur^1;
    asm volatile("s_waitcnt vmcnt(0)" ::: "memory");
    barrier_lgkm();                              // buf[cur] ready

    if (s < 15){
      // issue A(s+1) f32 loads, then B(s+1) gload_lds
      const f32x4* xp = reinterpret_cast<const f32x4*>(X + (size_t)(mbase+arow)*DD + (s+1)*32 + ahalf*16);
      #pragma unroll
      for (int q=0;q<4;q++) xa[q] = xp[q];
      unsigned short* lB = &AB[nxt][2][0][0] + w*512;
      #pragma unroll
      for (int r=0;r<2;r++){
        const size_t gh = (size_t)(nbase + r*64 + brow_l)*DD + (s+1)*32 + bkg*8;
        stage16(Wh + gh, lB + r*2048);
        stage16(Wl + gh, lB + 4096 + r*2048);
      }
    }

    // ---- compute step s from buf[cur] ----
    short8 ah[4], al[4], bh[4], bl[4];
    #pragma unroll
    for (int m=0;m<4;m++){
      const int rA = wr*64 + m*16 + l15;
      const int cg = (l4 ^ asw)*8;
      ah[m] = *reinterpret_cast<const short8*>(&AB[cur][0][rA][cg]);
      al[m] = *reinterpret_cast<const short8*>(&AB[cur][1][rA][cg]);
    }
    #pragma unroll
    for (int n=0;n<4;n++){
      const int rB = wc*64 + n*16 + l15;
      const int cg = (l4 ^ asw)*8;
      bh[n] = *reinterpret_cast<const short8*>(&AB[cur][2][rB][cg]);
      bl[n] = *reinterpret_cast<const short8*>(&AB[cur][3][rB][cg]);
    }
    #pragma unroll
    for (int m=0;m<4;m++)
      #pragma unroll
      for (int n=0;n<4;n++) acc[m][n] = __builtin_amdgcn_mfma_f32_16x16x32_bf16(ah[m], bh[n], acc[m][n], 0,0,0);
    #pragma unroll
    for (int m=0;m<4;m++)
      #pragma unroll
      for (int n=0;n<4;n++) acc[m][n] = __builtin_amdgcn_mfma_f32_16x16x32_bf16(ah[m], bl[n], acc[m][n], 0,0,0);
    #pragma unroll
    for (int m=0;m<4;m++)
      #pragma unroll
      for (int n=0;n<4;n++) acc[m][n] = __builtin_amdgcn_mfma_f32_16x16x32_bf16(al[m], bh[n], acc[m][n], 0,0,0);

    if (s < 15){
      // convert + write A(s+1) into buf[nxt]
      asm volatile("s_waitcnt vmcnt(4)" ::: "memory");
      short8 h0,h1,l0,l1;
      #pragma unroll
      for (int q=0;q<2;q++){
        #pragma unroll
        for (int j=0;j<4;j++){
          float v0 = xa[q*2][j], v1 = xa[q*2+1][j];
          unsigned short a = f2bf(v0); unsigned short b = f2bf(v1);
          if (q==0){ h0[j]=(short)a; h0[4+j]=(short)b; l0[j]=(short)f2bf(v0-bf2f(a)); l0[4+j]=(short)f2bf(v1-bf2f(b)); }
          else     { h1[j]=(short)a; h1[4+j]=(short)b; l1[j]=(short)f2bf(v0-bf2f(a)); l1[4+j]=(short)f2bf(v1-bf2f(b)); }
        }
      }
      const int sw = (arow>>1)&3;
      const int cg0 = (ahalf*2) ^ sw, cg1 = (ahalf*2+1) ^ sw;
      *reinterpret_cast<short8*>(&AB[nxt][0][arow][cg0*8]) = h0;
      *reinterpret_cast<short8*>(&AB[nxt][0][arow][cg1*8]) = h1;
      *reinterpret_cast<short8*>(&AB[nxt][1][arow][cg0*8]) = l0;
      *reinterpret_cast<short8*>(&AB[nxt][1][arow][cg1*8]) = l1;
    }
  }

  // ---- epilogue ----
  #pragma unroll
  for (int m=0;m<4;m++){
    #pragma unroll
    for (int n=0;n<4;n++){
      #pragma unroll
      for (int j=0;j<4;j++){
        const int row = mbase + wr*64 + m*16 + l4*4 + j;
        const int col = nbase + wc*64 + n*16 + l15;
        const float y = acc[m][n][j];
        const unsigned short h = f2bf(y);
        const unsigned short l = f2bf(y - bf2f(h));
        if (z == 0){
          const size_t idx = (size_t)row*DD + col;
          Yqh[idx] = h; Yql[idx] = l;
        } else {
          const int bb = row >> 11, nn = row & 2047, kt = nn >> 5;
          const size_t tb = ((size_t)(bb*64 + kt)) << 15;
          size_t idxH;
          if (z == 1){
            const int kr = nn & 31, cg = col >> 3, ci = col & 7;
            idxH = tb + ((size_t)kr)*512 + (size_t)((((cg ^ (kr & 7)) << 3)) | ci);
            Ykt[idxH] = h; Ykt[idxH + 16384] = l;
          } else {
            const int kk = nn & 31;
            idxH = tb + ((size_t)col)*32 + (size_t)(((((kk >> 3) ^ ((col >> 1) & 3)) << 3)) | (kk & 7));
            Yvt[idxH] = h; Yvt[idxH + 16384] = l;
          }
        }
      }
    }
  }
}

// ---------------- fused flash attention (split-bf16, LDS-staged, 4-barrier) ----------------
__global__ __launch_bounds__(512, 2) void attn_k(
    const unsigned short* __restrict__ Qhi, const unsigned short* __restrict__ Qlo,
    const unsigned short* __restrict__ Kt,  const unsigned short* __restrict__ Vt,
    float* __restrict__ Out)
{
  __shared__ unsigned short K_lds[2][32][512];   // 64 KB
  __shared__ unsigned short V_lds[2][512][32];   // 64 KB
  __shared__ float S_lds[64][33];
  __shared__ unsigned short Phi_s[64][40];
  __shared__ unsigned short Plo_s[64][40];
  __shared__ float m_s[64], l_s[64], sc_s[64];

  const int bid = blockIdx.x;
  const int b  = bid & 7;
  const int qt = bid >> 3;
  const int tid = threadIdx.x;
  const int w = tid >> 6, lane = tid & 63;
  const int l15 = lane & 15, l4 = lane >> 4;
  const int rw = w & 3,  cw = w >> 2;
  const int orw = w >> 2, ocw = w & 3;

  short8 qhf[16], qlf[16];
  {
    const size_t qoff = (size_t)(b*NQL + qt*64 + rw*16 + l15)*DD + l4*8;
    #pragma unroll
    for (int kc=0;kc<16;kc++){
      qhf[kc] = *reinterpret_cast<const short8*>(Qhi + qoff + kc*32);
      qlf[kc] = *reinterpret_cast<const short8*>(Qlo + qoff + kc*32);
    }
  }

  f32x4 o[2][8];
  #pragma unroll
  for (int i=0;i<2;i++)
    #pragma unroll
    for (int j=0;j<8;j++) o[i][j] = (f32x4){0.f,0.f,0.f,0.f};

  if (tid < 64){ m_s[tid] = -1e30f; l_s[tid] = 0.f; }

  const unsigned short* gK = Kt + ((size_t)(b*64) << 15);
  const unsigned short* gV = Vt + ((size_t)(b*64) << 15);
  unsigned short* lK = &K_lds[0][0][0];
  unsigned short* lV = &V_lds[0][0][0];
  const int goff  = w*512 + lane*8;
  const int lbase = w*512;

  #pragma unroll
  for (int r=0;r<8;r++) stage16(gK + r*4096 + goff, lK + r*4096 + lbase);

  const int krow = cw*16 + l15;
  const int kx = krow & 7;

  #pragma unroll 1
  for (int kt=0; kt<64; ++kt){
    // stage V(kt); outstanding: K(kt)=8 older + 8
    {
      const unsigned short* g = gV + ((size_t)kt << 15);
      #pragma unroll
      for (int r=0;r<8;r++) stage16(g + r*4096 + goff, lV + r*4096 + lbase);
    }
    asm volatile("s_waitcnt vmcnt(8)" ::: "memory");   // K(kt) resident
    barrier_lgkm();                                    // bar A

    // ---- S = Q K^T ----
    f32x4 shh = (f32x4){0.f,0.f,0.f,0.f};
    f32x4 shl = (f32x4){0.f,0.f,0.f,0.f};
    f32x4 slh = (f32x4){0.f,0.f,0.f,0.f};
    #pragma unroll
    for (int kc=0;kc<16;kc++){
      const int cg = ((kc*4 + l4) ^ kx) << 3;
      const short8 kh = *reinterpret_cast<const short8*>(&K_lds[0][krow][cg]);
      const short8 kl = *reinterpret_cast<const short8*>(&K_lds[1][krow][cg]);
      shh = __builtin_amdgcn_mfma_f32_16x16x32_bf16(qhf[kc], kh, shh, 0,0,0);
      shl = __builtin_amdgcn_mfma_f32_16x16x32_bf16(qhf[kc], kl, shl, 0,0,0);
      slh = __builtin_amdgcn_mfma_f32_16x16x32_bf16(qlf[kc], kh, slh, 0,0,0);
    }
    const f32x4 sv = shh + shl + slh;
    #pragma unroll
    for (int j=0;j<4;j++) S_lds[rw*16 + l4*4 + j][cw*16 + l15] = sv[j];
    barrier_lgkm();                                    // bar B — S ready, K_lds free

    // stage K(kt+1) — flies under softmax
    {
      const unsigned short* g = gK + ((size_t)((kt+1)&63) << 15);
      #pragma unroll
      for (int r=0;r<8;r++) stage16(g + r*4096 + goff, lK + r*4096 + lbase);
    }

    // ---- online softmax ----
    {
      const int row = tid >> 3, sub = tid & 7;
      const float v0=S_lds[row][sub*4+0], v1=S_lds[row][sub*4+1];
      const float v2=S_lds[row][sub*4+2], v3=S_lds[row][sub*4+3];
      float mx = fmaxf(fmaxf(v0,v1), fmaxf(v2,v3));
      mx = fmaxf(mx, __shfl_xor(mx, 1, 64));
      mx = fmaxf(mx, __shfl_xor(mx, 2, 64));
      mx = fmaxf(mx, __shfl_xor(mx, 4, 64));
      const float m_old = m_s[row];
      const float m_new = fmaxf(m_old, mx);
      const float p0=__expf(v0-m_new), p1=__expf(v1-m_new);
      const float p2=__expf(v2-m_new), p3=__expf(v3-m_new);
      float sm = p0+p1+p2+p3;
      sm += __shfl_xor(sm,1,64); sm += __shfl_xor(sm,2,64); sm += __shfl_xor(sm,4,64);
      if (sub==0){
        const float sc = __expf(m_old - m_new);
        sc_s[row] = sc;
        l_s[row] = l_s[row]*sc + sm;
        m_s[row] = m_new;
      }
      const unsigned short h0=f2bf(p0), h1=f2bf(p1), h2=f2bf(p2), h3=f2bf(p3);
      *reinterpret_cast<unsigned*>(&Phi_s[row][sub*4])   = (unsigned)h0 | ((unsigned)h1<<16);
      *reinterpret_cast<unsigned*>(&Phi_s[row][sub*4+2]) = (unsigned)h2 | ((unsigned)h3<<16);
      const unsigned short g0=f2bf(p0-bf2f(h0)), g1=f2bf(p1-bf2f(h1));
      const unsigned short g2=f2bf(p2-bf2f(h2)), g3=f2bf(p3-bf2f(h3));
      *reinterpret_cast<unsigned*>(&Plo_s[row][sub*4])   = (unsigned)g0 | ((unsigned)g1<<16);
      *reinterpret_cast<unsigned*>(&Plo_s[row][sub*4+2]) = (unsigned)g2 | ((unsigned)g3<<16);
    }
    asm volatile("s_waitcnt vmcnt(8)" ::: "memory");    // V(kt) resident (8 K newer)
    barrier_lgkm();                                     // bar C — P ready, V ready

    // ---- rescale O ----
    {
      float scs[2][4];
      bool need = false;
      #pragma unroll
      for (int pr=0; pr<2; pr++)
        #pragma unroll
        for (int j=0;j<4;j++){
          const float s0 = sc_s[orw*32 + pr*16 + l4*4 + j];
          scs[pr][j] = s0;
          need = need || (s0 < 0.999999f);
        }
      if (__any(need)){
        #pragma unroll
        for (int pr=0;pr<2;pr++)
          #pragma unroll
          for (int c=0;c<8;c++)
            #pragma unroll
            for (int j=0;j<4;j++) o[pr][c][j] *= scs[pr][j];
      }
    }

    // ---- O += P V ----
    short8 pah[2], pal[2];
    #pragma unroll
    for (int pr=0;pr<2;pr++){
      const int prow = orw*32 + pr*16 + l15;
      pah[pr] = *reinterpret_cast<const short8*>(&Phi_s[prow][l4*8]);
      pal[pr] = *reinterpret_cast<const short8*>(&Plo_s[prow][l4*8]);
    }
    #pragma unroll
    for (int cc=0; cc<8; ++cc){
      const int dcol = ocw*128 + cc*16 + l15;
      const int vb = (l4 ^ ((dcol>>1)&3)) << 3;
      const short8 vh = *reinterpret_cast<const short8*>(&V_lds[0][dcol][vb]);
      const short8 vl = *reinterpret_cast<const short8*>(&V_lds[1][dcol][vb]);
      o[0][cc] = __builtin_amdgcn_mfma_f32_16x16x32_bf16(pah[0], vh, o[0][cc], 0,0,0);
      o[1][cc] = __builtin_amdgcn_mfma_f32_16x16x32_bf16(pah[1], vh, o[1][cc], 0,0,0);
      o[0][cc] = __builtin_amdgcn_mfma_f32_16x16x32_bf16(pal[0], vh, o[0][cc], 0,0,0);
      o[1][cc] = __builtin_amdgcn_mfma_f32_16x16x32_bf16(pal[1], vh, o[1][cc], 0,0,0);
      o[0][cc] = __builtin_amdgcn_mfma_f32_16x16x32_bf16(pah[0], vl, o[0][cc], 0,0,0);
      o[1][cc] = __builtin_amdgcn_mfma_f32_16x16x32_bf16(pah[1], vl, o[1][cc], 0,0,0);
    }
    barrier_lgkm();                                     // bar D — V/P free
  }

  #pragma unroll
  for (int pr=0;pr<2;pr++){
    #pragma unroll
    for (int j=0;j<4;j++){
      const int row = orw*32 + pr*16 + l4*4 + j;
      const float inv = 1.0f / l_s[row];
      const size_t obase = (size_t)(b*NQL + qt*64 + row)*DD;
      #pragma unroll
      for (int c=0;c<8;c++){
        const int col = ocw*128 + c*16 + l15;
        Out[obase + col] = o[pr][c][j]*inv;
      }
    }
  }
}

extern "C" void kernel_launch(void* const* d_in, const int* in_sizes, int n_in,
                              void* d_out, int out_size, void* d_ws, size_t ws_size,
                              hipStream_t stream) {
  const float* query = (const float*)d_in[0];
  const float* key   = (const float*)d_in[1];
  const float* value = (const float*)d_in[2];
  const float* Wq    = (const float*)d_in[3];
  const float* Wk    = (const float*)d_in[4];
  const float* Wv    = (const float*)d_in[5];
  float* out = (float*)d_out;

  const size_t SB = (size_t)NB*NQL*DD;
  const size_t WB = (size_t)DD*DD;

  unsigned short* p = (unsigned short*)d_ws;
  unsigned short *wqh = p,        *wql = p +   WB;
  unsigned short *wkh = p + 2*WB, *wkl = p + 3*WB;
  unsigned short *wvh = p + 4*WB, *wvl = p + 5*WB;
  unsigned short* q0 = p + 6*WB;
  unsigned short *qh  = q0,        *ql  = q0 + SB;
  unsigned short *Ktl = q0 + 2*SB;            // [8][64][2][32][512]
  unsigned short *Vtl = q0 + 4*SB;            // [8][64][2][512][32]

  split_k<<<256, 256, 0, stream>>>(Wq, wqh, wql, (int)(WB/4));
  split_k<<<256, 256, 0, stream>>>(Wk, wkh, wkl, (int)(WB/4));
  split_k<<<256, 256, 0, stream>>>(Wv, wvh, wvl, (int)(WB/4));

  dim3 pg(128, 4, 3);
  proj2_k<<<pg, 256, 0, stream>>>(query, key, value,
                                  wqh, wql, wkh, wkl, wvh, wvl,
                                  qh, ql, Ktl, Vtl);

  attn_k<<<256, 512, 0, stream>>>(qh, ql, Ktl, Vtl, out);
}

// Round 4
// 346.768 us; speedup vs baseline: 3.8520x; 1.0432x over previous
//
#include <hip/hip_runtime.h>

typedef __attribute__((ext_vector_type(8))) short short8;
typedef __attribute__((ext_vector_type(4))) float f32x4;
typedef __attribute__((ext_vector_type(4))) unsigned short u16x4;

#define NB 8
#define NQL 2048
#define NKL 2048
#define DD 512

static __device__ __forceinline__ unsigned short f2bf(float x){
  unsigned u = __builtin_bit_cast(unsigned, x);
  unsigned r = u + 0x7FFFu + ((u >> 16) & 1u);
  return (unsigned short)(r >> 16);
}
static __device__ __forceinline__ float bf2f(unsigned short h){
  unsigned u = ((unsigned)h) << 16;
  return __builtin_bit_cast(float, u);
}

static __device__ __forceinline__ void stage16(const unsigned short* g, unsigned short* l){
  __builtin_amdgcn_global_load_lds(
      (const __attribute__((address_space(1))) void*)g,
      (__attribute__((address_space(3))) void*)l, 16, 0, 0);
}

static __device__ __forceinline__ void barrier_lgkm(){
  asm volatile("s_waitcnt lgkmcnt(0)" ::: "memory");
  __builtin_amdgcn_s_barrier();
  asm volatile("" ::: "memory");
}

// ---------------- split fp32 -> bf16 hi/lo (W matrices only) ----------------
__global__ __launch_bounds__(256) void split_k(const float* __restrict__ x,
    unsigned short* __restrict__ hi, unsigned short* __restrict__ lo, int n4){
  int i = blockIdx.x*256 + threadIdx.x;
  if (i >= n4) return;
  f32x4 v = reinterpret_cast<const f32x4*>(x)[i];
  u16x4 h, l;
  #pragma unroll
  for (int j=0;j<4;j++){
    unsigned short hh = f2bf(v[j]);
    h[j] = hh;
    l[j] = f2bf(v[j] - bf2f(hh));
  }
  reinterpret_cast<u16x4*>(hi)[i] = h;
  reinterpret_cast<u16x4*>(lo)[i] = l;
}

// ---------------- fused projections: Y = X * W^T (128x128 tile, staged, dbuf) ----------------
__global__ __launch_bounds__(256, 2) void proj2_k(
    const float* __restrict__ Xq, const float* __restrict__ Xk, const float* __restrict__ Xv,
    const unsigned short* __restrict__ Wqh, const unsigned short* __restrict__ Wql,
    const unsigned short* __restrict__ Wkh, const unsigned short* __restrict__ Wkl,
    const unsigned short* __restrict__ Wvh, const unsigned short* __restrict__ Wvl,
    unsigned short* __restrict__ Yqh, unsigned short* __restrict__ Yql,
    unsigned short* __restrict__ Ykt, unsigned short* __restrict__ Yvt)
{
  __shared__ unsigned short AB[2][4][128][32];   // 64 KB

  const int z = blockIdx.z;
  const float* X          = (z==0) ? Xq  : (z==1) ? Xk  : Xv;
  const unsigned short* Wh = (z==0) ? Wqh : (z==1) ? Wkh : Wvh;
  const unsigned short* Wl = (z==0) ? Wql : (z==1) ? Wkl : Wvl;

  const int mbase = blockIdx.x * 128;
  const int nbase = blockIdx.y * 128;
  const int tid = threadIdx.x;
  const int w = tid >> 6, lane = tid & 63;
  const int l15 = lane & 15, l4 = lane >> 4;
  const int wr = w >> 1, wc = w & 1;

  const int arow = tid >> 1, ahalf = tid & 1;
  const int brow_l = w*16 + (lane>>2);
  const int bkg    = (lane & 3) ^ ((lane >> 3) & 3);

  f32x4 acc[4][4];
  #pragma unroll
  for (int m=0;m<4;m++)
    #pragma unroll
    for (int n=0;n<4;n++) acc[m][n] = (f32x4){0.f,0.f,0.f,0.f};

  f32x4 xa[4];
  {
    const f32x4* xp = reinterpret_cast<const f32x4*>(X + (size_t)(mbase+arow)*DD + ahalf*16);
    #pragma unroll
    for (int q=0;q<4;q++) xa[q] = xp[q];
  }
  {
    unsigned short* lB = &AB[0][2][0][0] + w*512;
    #pragma unroll
    for (int r=0;r<2;r++){
      const size_t gh = (size_t)(nbase + r*64 + brow_l)*DD + bkg*8;
      stage16(Wh + gh, lB + r*2048);
      stage16(Wl + gh, lB + 4096 + r*2048);
    }
  }
  {
    asm volatile("s_waitcnt vmcnt(4)" ::: "memory");
    short8 h0,h1,l0,l1;
    #pragma unroll
    for (int q=0;q<2;q++){
      #pragma unroll
      for (int j=0;j<4;j++){
        float v0 = xa[q*2][j], v1 = xa[q*2+1][j];
        unsigned short a = f2bf(v0); unsigned short b = f2bf(v1);
        if (q==0){ h0[j]=(short)a; h0[4+j]=(short)b; l0[j]=(short)f2bf(v0-bf2f(a)); l0[4+j]=(short)f2bf(v1-bf2f(b)); }
        else     { h1[j]=(short)a; h1[4+j]=(short)b; l1[j]=(short)f2bf(v0-bf2f(a)); l1[4+j]=(short)f2bf(v1-bf2f(b)); }
      }
    }
    const int sw = (arow>>1)&3;
    const int cg0 = (ahalf*2) ^ sw, cg1 = (ahalf*2+1) ^ sw;
    *reinterpret_cast<short8*>(&AB[0][0][arow][cg0*8]) = h0;
    *reinterpret_cast<short8*>(&AB[0][0][arow][cg1*8]) = h1;
    *reinterpret_cast<short8*>(&AB[0][1][arow][cg0*8]) = l0;
    *reinterpret_cast<short8*>(&AB[0][1][arow][cg1*8]) = l1;
  }

  const int asw = (l15>>1)&3;

  #pragma unroll 1
  for (int s=0; s<16; ++s){
    const int cur = s&1, nxt = cur^1;
    asm volatile("s_waitcnt vmcnt(0)" ::: "memory");
    barrier_lgkm();

    if (s < 15){
      const f32x4* xp = reinterpret_cast<const f32x4*>(X + (size_t)(mbase+arow)*DD + (s+1)*32 + ahalf*16);
      #pragma unroll
      for (int q=0;q<4;q++) xa[q] = xp[q];
      unsigned short* lB = &AB[nxt][2][0][0] + w*512;
      #pragma unroll
      for (int r=0;r<2;r++){
        const size_t gh = (size_t)(nbase + r*64 + brow_l)*DD + (s+1)*32 + bkg*8;
        stage16(Wh + gh, lB + r*2048);
        stage16(Wl + gh, lB + 4096 + r*2048);
      }
    }

    short8 ah[4], al[4], bh[4], bl[4];
    #pragma unroll
    for (int m=0;m<4;m++){
      const int rA = wr*64 + m*16 + l15;
      const int cg = (l4 ^ asw)*8;
      ah[m] = *reinterpret_cast<const short8*>(&AB[cur][0][rA][cg]);
      al[m] = *reinterpret_cast<const short8*>(&AB[cur][1][rA][cg]);
    }
    #pragma unroll
    for (int n=0;n<4;n++){
      const int rB = wc*64 + n*16 + l15;
      const int cg = (l4 ^ asw)*8;
      bh[n] = *reinterpret_cast<const short8*>(&AB[cur][2][rB][cg]);
      bl[n] = *reinterpret_cast<const short8*>(&AB[cur][3][rB][cg]);
    }
    #pragma unroll
    for (int m=0;m<4;m++)
      #pragma unroll
      for (int n=0;n<4;n++) acc[m][n] = __builtin_amdgcn_mfma_f32_16x16x32_bf16(ah[m], bh[n], acc[m][n], 0,0,0);
    #pragma unroll
    for (int m=0;m<4;m++)
      #pragma unroll
      for (int n=0;n<4;n++) acc[m][n] = __builtin_amdgcn_mfma_f32_16x16x32_bf16(ah[m], bl[n], acc[m][n], 0,0,0);
    #pragma unroll
    for (int m=0;m<4;m++)
      #pragma unroll
      for (int n=0;n<4;n++) acc[m][n] = __builtin_amdgcn_mfma_f32_16x16x32_bf16(al[m], bh[n], acc[m][n], 0,0,0);

    if (s < 15){
      asm volatile("s_waitcnt vmcnt(4)" ::: "memory");
      short8 h0,h1,l0,l1;
      #pragma unroll
      for (int q=0;q<2;q++){
        #pragma unroll
        for (int j=0;j<4;j++){
          float v0 = xa[q*2][j], v1 = xa[q*2+1][j];
          unsigned short a = f2bf(v0); unsigned short b = f2bf(v1);
          if (q==0){ h0[j]=(short)a; h0[4+j]=(short)b; l0[j]=(short)f2bf(v0-bf2f(a)); l0[4+j]=(short)f2bf(v1-bf2f(b)); }
          else     { h1[j]=(short)a; h1[4+j]=(short)b; l1[j]=(short)f2bf(v0-bf2f(a)); l1[4+j]=(short)f2bf(v1-bf2f(b)); }
        }
      }
      const int sw = (arow>>1)&3;
      const int cg0 = (ahalf*2) ^ sw, cg1 = (ahalf*2+1) ^ sw;
      *reinterpret_cast<short8*>(&AB[nxt][0][arow][cg0*8]) = h0;
      *reinterpret_cast<short8*>(&AB[nxt][0][arow][cg1*8]) = h1;
      *reinterpret_cast<short8*>(&AB[nxt][1][arow][cg0*8]) = l0;
      *reinterpret_cast<short8*>(&AB[nxt][1][arow][cg1*8]) = l1;
    }
  }

  #pragma unroll
  for (int m=0;m<4;m++){
    #pragma unroll
    for (int n=0;n<4;n++){
      #pragma unroll
      for (int j=0;j<4;j++){
        const int row = mbase + wr*64 + m*16 + l4*4 + j;
        const int col = nbase + wc*64 + n*16 + l15;
        const float y = acc[m][n][j];
        const unsigned short h = f2bf(y);
        const unsigned short l = f2bf(y - bf2f(h));
        if (z == 0){
          const size_t idx = (size_t)row*DD + col;
          Yqh[idx] = h; Yql[idx] = l;
        } else {
          const int bb = row >> 11, nn = row & 2047, kt = nn >> 5;
          const size_t tb = ((size_t)(bb*64 + kt)) << 15;
          size_t idxH;
          if (z == 1){
            const int kr = nn & 31, cg = col >> 3, ci = col & 7;
            idxH = tb + ((size_t)kr)*512 + (size_t)((((cg ^ (kr & 7)) << 3)) | ci);
            Ykt[idxH] = h; Ykt[idxH + 16384] = l;
          } else {
            const int kk = nn & 31;
            idxH = tb + ((size_t)col)*32 + (size_t)(((((kk >> 3) ^ ((col >> 1) & 3)) << 3)) | (kk & 7));
            Yvt[idxH] = h; Yvt[idxH + 16384] = l;
          }
        }
      }
    }
  }
}

// ---------------- fused flash attention: swapped QK^T + in-register softmax ----------------
// Grid 256 (b = bid&7, qt = bid>>3), 512 threads (8 waves, grid 4i x 2j on S).
// S^T = mfma(K_frag, Q_frag): lane holds 4 S-values of ONE q-row -> in-reg softmax.
// 3 barriers/iter. K(t+1) staged after barB, V(t) after barA, counted vmcnt.
__global__ __launch_bounds__(512, 2) void attn_k(
    const unsigned short* __restrict__ Qhi, const unsigned short* __restrict__ Qlo,
    const unsigned short* __restrict__ Kt,  const unsigned short* __restrict__ Vt,
    float* __restrict__ Out)
{
  __shared__ unsigned short K_lds[2][32][512];   // 64 KB
  __shared__ unsigned short V_lds[2][512][32];   // 64 KB
  __shared__ unsigned short Phi_s[64][40];
  __shared__ unsigned short Plo_s[64][40];       // 10 KB
  __shared__ float pm_s[64][2], ps_s[64][2];     // 1 KB
  __shared__ float m_s[2][64], l_s[64], sc_s[64];

  const int bid = blockIdx.x;
  const int b  = bid & 7;
  const int qt = bid >> 3;
  const int tid = threadIdx.x;
  const int w = tid >> 6, lane = tid & 63;
  const int l15 = lane & 15, l4 = lane >> 4;
  const int rw = w & 3,  cw = w >> 2;   // S^T frag: q-rows rw*16.., k-cols cw*16..
  const int orw = w >> 2, ocw = w & 3;  // O: rows orw*32.., cols ocw*128..

  short8 qhf[16], qlf[16];
  {
    const size_t qoff = (size_t)(b*NQL + qt*64 + rw*16 + l15)*DD + l4*8;
    #pragma unroll
    for (int kc=0;kc<16;kc++){
      qhf[kc] = *reinterpret_cast<const short8*>(Qhi + qoff + kc*32);
      qlf[kc] = *reinterpret_cast<const short8*>(Qlo + qoff + kc*32);
    }
  }

  f32x4 o[2][8];
  #pragma unroll
  for (int i=0;i<2;i++)
    #pragma unroll
    for (int j=0;j<8;j++) o[i][j] = (f32x4){0.f,0.f,0.f,0.f};

  if (tid < 64){ m_s[0][tid] = -1e30f; l_s[tid] = 0.f; }

  const unsigned short* gK = Kt + ((size_t)(b*64) << 15);
  const unsigned short* gV = Vt + ((size_t)(b*64) << 15);
  unsigned short* lK = &K_lds[0][0][0];
  unsigned short* lV = &V_lds[0][0][0];
  const int goff  = w*512 + lane*8;
  const int lbase = w*512;

  // prologue: stage K(0)
  #pragma unroll
  for (int r=0;r<8;r++) stage16(gK + r*4096 + goff, lK + r*4096 + lbase);

  const int krow = cw*16 + l15;
  const int kx = krow & 7;
  const int row_i = rw*16 + l15;     // this lane's q-row (local)

  #pragma unroll 1
  for (int kt=0; kt<64; ++kt){
    const int par = kt & 1;
    asm volatile("s_waitcnt vmcnt(0)" ::: "memory");   // K(kt) resident
    barrier_lgkm();                                    // bar A (also: PV(t-1) reads drained)

    // stage V(kt) — lands by barC, hidden under QK^T+softmax
    {
      const unsigned short* g = gV + ((size_t)kt << 15);
      #pragma unroll
      for (int r=0;r<8;r++) stage16(g + r*4096 + goff, lV + r*4096 + lbase);
    }

    // ---- S^T = K Q^T (swapped operands; same LDS reads) ----
    f32x4 shh = (f32x4){0.f,0.f,0.f,0.f};
    f32x4 shl = (f32x4){0.f,0.f,0.f,0.f};
    f32x4 slh = (f32x4){0.f,0.f,0.f,0.f};
    __builtin_amdgcn_s_setprio(1);
    #pragma unroll
    for (int kc=0;kc<16;kc++){
      const int cg = ((kc*4 + l4) ^ kx) << 3;
      const short8 kh = *reinterpret_cast<const short8*>(&K_lds[0][krow][cg]);
      const short8 kl = *reinterpret_cast<const short8*>(&K_lds[1][krow][cg]);
      shh = __builtin_amdgcn_mfma_f32_16x16x32_bf16(kh, qhf[kc], shh, 0,0,0);
      shl = __builtin_amdgcn_mfma_f32_16x16x32_bf16(kl, qhf[kc], shl, 0,0,0);
      slh = __builtin_amdgcn_mfma_f32_16x16x32_bf16(kh, qlf[kc], slh, 0,0,0);
    }
    __builtin_amdgcn_s_setprio(0);
    const f32x4 sv = shh + shl + slh;   // sv[r] = S[row_i][cw*16 + l4*4 + r]

    // ---- per-wave softmax partials (all 64 lanes) ----
    float mw = fmaxf(fmaxf(sv[0],sv[1]), fmaxf(sv[2],sv[3]));
    mw = fmaxf(mw, __shfl_xor(mw, 16));
    mw = fmaxf(mw, __shfl_xor(mw, 32));
    float p0 = __expf(sv[0]-mw), p1 = __expf(sv[1]-mw);
    float p2 = __expf(sv[2]-mw), p3 = __expf(sv[3]-mw);
    float sw = p0+p1+p2+p3;
    sw += __shfl_xor(sw, 16);
    sw += __shfl_xor(sw, 32);
    if (l4 == 0){ pm_s[row_i][cw] = mw; ps_s[row_i][cw] = sw; }
    barrier_lgkm();                                    // bar B — partials ready, K_lds free

    // stage K(kt+1) — hidden under combine + PV
    {
      const unsigned short* g = gK + ((size_t)((kt+1)&63) << 15);
      #pragma unroll
      for (int r=0;r<8;r++) stage16(g + r*4096 + goff, lK + r*4096 + lbase);
    }

    // ---- combine partials, finalize P, write P hi/lo ----
    {
      const float m0 = pm_s[row_i][0], m1 = pm_s[row_i][1];
      const float m_old = m_s[par][row_i];
      const float m_new = fmaxf(fmaxf(m0, m1), m_old);
      const float c = __expf(mw - m_new);
      p0 *= c; p1 *= c; p2 *= c; p3 *= c;
      if (cw == 0 && l4 == 0){
        const float e_old = __expf(m_old - m_new);
        const float e1    = __expf(m1 - m_new);
        l_s[row_i] = l_s[row_i]*e_old + ps_s[row_i][0]*c + ps_s[row_i][1]*e1;
        m_s[par^1][row_i] = m_new;
        sc_s[row_i] = e_old;
      }
      const unsigned short h0=f2bf(p0), h1=f2bf(p1), h2=f2bf(p2), h3=f2bf(p3);
      uint2 hv, lv;
      hv.x = (unsigned)h0 | ((unsigned)h1<<16);
      hv.y = (unsigned)h2 | ((unsigned)h3<<16);
      lv.x = (unsigned)f2bf(p0-bf2f(h0)) | ((unsigned)f2bf(p1-bf2f(h1))<<16);
      lv.y = (unsigned)f2bf(p2-bf2f(h2)) | ((unsigned)f2bf(p3-bf2f(h3))<<16);
      *reinterpret_cast<uint2*>(&Phi_s[row_i][cw*16 + l4*4]) = hv;
      *reinterpret_cast<uint2*>(&Plo_s[row_i][cw*16 + l4*4]) = lv;
    }
    asm volatile("s_waitcnt vmcnt(8)" ::: "memory");   // V(kt) resident (K(kt+1) outstanding)
    barrier_lgkm();                                    // bar C — P ready, V ready

    // ---- rescale O (skip when running max unchanged) ----
    {
      float scs[2][4];
      bool need = false;
      #pragma unroll
      for (int pr=0; pr<2; pr++)
        #pragma unroll
        for (int j=0;j<4;j++){
          const float s0 = sc_s[orw*32 + pr*16 + l4*4 + j];
          scs[pr][j] = s0;
          need = need || (s0 < 0.999999f);
        }
      if (__any(need)){
        #pragma unroll
        for (int pr=0;pr<2;pr++)
          #pragma unroll
          for (int c=0;c<8;c++)
            #pragma unroll
            for (int j=0;j<4;j++) o[pr][c][j] *= scs[pr][j];
      }
    }

    // ---- O += P V ----
    short8 pah[2], pal[2];
    #pragma unroll
    for (int pr=0;pr<2;pr++){
      const int prow = orw*32 + pr*16 + l15;
      pah[pr] = *reinterpret_cast<const short8*>(&Phi_s[prow][l4*8]);
      pal[pr] = *reinterpret_cast<const short8*>(&Plo_s[prow][l4*8]);
    }
    __builtin_amdgcn_s_setprio(1);
    #pragma unroll
    for (int cc=0; cc<8; ++cc){
      const int dcol = ocw*128 + cc*16 + l15;
      const int vb = (l4 ^ ((dcol>>1)&3)) << 3;
      const short8 vh = *reinterpret_cast<const short8*>(&V_lds[0][dcol][vb]);
      const short8 vl = *reinterpret_cast<const short8*>(&V_lds[1][dcol][vb]);
      o[0][cc] = __builtin_amdgcn_mfma_f32_16x16x32_bf16(pah[0], vh, o[0][cc], 0,0,0);
      o[1][cc] = __builtin_amdgcn_mfma_f32_16x16x32_bf16(pah[1], vh, o[1][cc], 0,0,0);
      o[0][cc] = __builtin_amdgcn_mfma_f32_16x16x32_bf16(pal[0], vh, o[0][cc], 0,0,0);
      o[1][cc] = __builtin_amdgcn_mfma_f32_16x16x32_bf16(pal[1], vh, o[1][cc], 0,0,0);
      o[0][cc] = __builtin_amdgcn_mfma_f32_16x16x32_bf16(pah[0], vl, o[0][cc], 0,0,0);
      o[1][cc] = __builtin_amdgcn_mfma_f32_16x16x32_bf16(pah[1], vl, o[1][cc], 0,0,0);
    }
    __builtin_amdgcn_s_setprio(0);
    // no bar D: barA's per-wave lgkmcnt(0) drains PV reads before V(t+1) staging writes land
  }

  barrier_lgkm();   // l_s final visible

  #pragma unroll
  for (int pr=0;pr<2;pr++){
    #pragma unroll
    for (int j=0;j<4;j++){
      const int row = orw*32 + pr*16 + l4*4 + j;
      const float inv = 1.0f / l_s[row];
      const size_t obase = (size_t)(b*NQL + qt*64 + row)*DD;
      #pragma unroll
      for (int c=0;c<8;c++){
        const int col = ocw*128 + c*16 + l15;
        Out[obase + col] = o[pr][c][j]*inv;
      }
    }
  }
}

extern "C" void kernel_launch(void* const* d_in, const int* in_sizes, int n_in,
                              void* d_out, int out_size, void* d_ws, size_t ws_size,
                              hipStream_t stream) {
  const float* query = (const float*)d_in[0];
  const float* key   = (const float*)d_in[1];
  const float* value = (const float*)d_in[2];
  const float* Wq    = (const float*)d_in[3];
  const float* Wk    = (const float*)d_in[4];
  const float* Wv    = (const float*)d_in[5];
  float* out = (float*)d_out;

  const size_t SB = (size_t)NB*NQL*DD;
  const size_t WB = (size_t)DD*DD;

  unsigned short* p = (unsigned short*)d_ws;
  unsigned short *wqh = p,        *wql = p +   WB;
  unsigned short *wkh = p + 2*WB, *wkl = p + 3*WB;
  unsigned short *wvh = p + 4*WB, *wvl = p + 5*WB;
  unsigned short* q0 = p + 6*WB;
  unsigned short *qh  = q0,        *ql  = q0 + SB;
  unsigned short *Ktl = q0 + 2*SB;            // [8][64][2][32][512]
  unsigned short *Vtl = q0 + 4*SB;            // [8][64][2][512][32]

  split_k<<<256, 256, 0, stream>>>(Wq, wqh, wql, (int)(WB/4));
  split_k<<<256, 256, 0, stream>>>(Wk, wkh, wkl, (int)(WB/4));
  split_k<<<256, 256, 0, stream>>>(Wv, wvh, wvl, (int)(WB/4));

  dim3 pg(128, 4, 3);
  proj2_k<<<pg, 256, 0, stream>>>(query, key, value,
                                  wqh, wql, wkh, wkl, wvh, wvl,
                                  qh, ql, Ktl, Vtl);

  attn_k<<<256, 512, 0, stream>>>(qh, ql, Ktl, Vtl, out);
}